// Round 11
// baseline (929.980 us; speedup 1.0000x reference)
//
#include <hip/hip_runtime.h>
#include <hip/hip_bf16.h>
#include <stdint.h>

#define NN 50000
#define EE 800000

typedef unsigned short u16;
typedef __attribute__((ext_vector_type(4))) float f32x4;
typedef __attribute__((ext_vector_type(8))) short bf16x8;

__device__ __forceinline__ float bu2f(u16 u){ return __uint_as_float(((unsigned)u)<<16); }
__device__ __forceinline__ u16 f2bu(float f){
  unsigned u = __float_as_uint(f);
  u += 0x7fffu + ((u>>16)&1u);      // round-to-nearest-even
  return (u16)(u>>16);
}
__device__ __forceinline__ float lo16f(unsigned u){ return __uint_as_float(u << 16); }
__device__ __forceinline__ float hi16f(unsigned u){ return __uint_as_float(u & 0xffff0000u); }

// ---------- sniff: flags[0] = edges are int64; flags[1] = float inputs are bf16 ----------
__global__ void sniff_kernel(const int* __restrict__ e, const u16* __restrict__ xu,
                             int* __restrict__ flags){
  __shared__ int nz, cnt;
  int t = threadIdx.x;
  if (t == 0){ nz = 0; cnt = 0; }
  __syncthreads();
  if (e[2*t + 1] != 0) atomicOr(&nz, 1);
  u16 u = xu[2*t];
  int ef = (u >> 7) & 0xFF;
  int ok = (u == 0) || (ef >= 118 && ef <= 132);
  atomicAdd(&cnt, ok);
  __syncthreads();
  if (t == 0){ flags[0] = (nz == 0) ? 1 : 0; flags[1] = (cnt >= 200) ? 1 : 0; }
}

// ---------- convert edges + degree (dst half) in one pass ----------
__global__ void convert_edges_kernel(const void* __restrict__ ep, int* __restrict__ outp,
                                     int* __restrict__ degI,
                                     const int* __restrict__ flags, int total){
  int i = blockIdx.x*256 + threadIdx.x;
  if (i >= total) return;
  int v;
  if (flags[0]) v = (int)((const long long*)ep)[i];
  else          v = ((const int*)ep)[i];
  outp[i] = v;
  if (i >= EE) atomicAdd(&degI[v], 1);   // dst entries
}

// ---------- canonicalize params: optional K-pad, to bf16 or fp32 ----------
struct CanonTab {
  const void* src[15];
  void*       dst[15];
  int rows[15];
  int sk[15];
  int dk[15];
  int tobf[15];
};

__global__ __launch_bounds__(256) void canon_params_kernel(CanonTab tab, const int* __restrict__ flags){
  int a = blockIdx.y;
  int isbf = flags[1];
  int rows = tab.rows[a], sk = tab.sk[a], dk = tab.dk[a], tobf = tab.tobf[a];
  int n = rows * dk;
  int base = (blockIdx.x*256 + threadIdx.x) * 8;
  if (base >= n) return;
  #pragma unroll
  for (int uu = 0; uu < 8; uu++){
    int i = base + uu;
    if (i >= n) break;
    int r = i / dk, c = i - r*dk;
    float v = 0.f;
    if (c < sk){
      size_t si = (size_t)r*sk + c;
      v = isbf ? bu2f(((const u16*)tab.src[a])[si]) : ((const float*)tab.src[a])[si];
    }
    if (tobf) ((u16*)tab.dst[a])[i] = f2bu(v);
    else      ((float*)tab.dst[a])[i] = v;
  }
}

// ---------- conv3x3 VALID + bias + concat(bd) + relu -> h0 bf16 [NN][704] ----------
// 8 nodes/block, 256 thr: quarter q = t>>6 (WAVE-UNIFORM), node = (t>>3)&7, co = t&7.
// q0: out rows 0-2 (acc[27]); q1: 3-4; q2: 5-6; q3: 7-8 (acc[18] each). ~90 VGPR,
// LDS ~20 KB -> 4-5 blocks/CU (occupancy fix). x bf16 in LDS, rows padded 11->12,
// node stride 1096 (548 words ≡ 4 mod 32: 8 nodes on distinct bank-pairs, co broadcast).
#define XND 1096
#define CROW_LOAD(R) { \
  uint2 p0 = *(const uint2*)&xrow[xb]; \
  uint2 p1 = *(const uint2*)&xrow[xb+4]; \
  uint2 p2 = *(const uint2*)&xrow[xb+8]; \
  R[0]=lo16f(p0.x); R[1]=hi16f(p0.x); R[2]=lo16f(p0.y); R[3]=hi16f(p0.y); \
  R[4]=lo16f(p1.x); R[5]=hi16f(p1.x); R[6]=lo16f(p1.y); R[7]=hi16f(p1.y); \
  R[8]=lo16f(p2.x); R[9]=hi16f(p2.x); R[10]=lo16f(p2.y); \
  xb += 12; }
#define CACC9(A,B,C,LOI) { _Pragma("unroll") for (int oj = 0; oj < 9; oj++){ \
    acc[(LOI)*9+oj] += A[oj]*w[0] + A[oj+1]*w[1] + A[oj+2]*w[2] \
                     + B[oj]*w[3] + B[oj+1]*w[4] + B[oj+2]*w[5] \
                     + C[oj]*w[6] + C[oj+1]*w[7] + C[oj+2]*w[8]; } }

__global__ __launch_bounds__(256, 4) void conv_relu_kernel(
    const void* __restrict__ xraw, const void* __restrict__ bdraw,
    const float* __restrict__ cw, const float* __restrict__ cb,
    const int* __restrict__ flags, u16* __restrict__ h0){
  __shared__ u16 xs[8*XND];     // 17.5 KB
  __shared__ float wsm[576];
  __shared__ float bs[8];
  int t = threadIdx.x;
  int nb = blockIdx.x << 3;
  int isbf = flags[1];
  if (t < 144){ float4 u = ((const float4*)cw)[t]; wsm[4*t]=u.x; wsm[4*t+1]=u.y; wsm[4*t+2]=u.z; wsm[4*t+3]=u.w; }
  if (t < 8) bs[t] = cb[t];
  // stage x -> bf16 LDS with row pad 11->12
  if (isbf){
    const u16* xg = (const u16*)xraw + (size_t)nb*968;
    for (int i = t; i < 968; i += 256){
      ushort4 v0 = ((const ushort4*)xg)[2*i];
      ushort4 v1 = ((const ushort4*)xg)[2*i+1];
      u16 e[8] = {v0.x,v0.y,v0.z,v0.w,v1.x,v1.y,v1.z,v1.w};
      int g = i*8;
      #pragma unroll
      for (int k = 0; k < 8; k++){
        int gg = g + k;
        int node = gg / 968, rem = gg - node*968;
        int ci = rem / 121, rem2 = rem - ci*121;
        int r = rem2 / 11, c = rem2 - r*11;
        xs[node*XND + ci*132 + r*12 + c] = e[k];
      }
    }
  } else {
    const float* xg = (const float*)xraw + (size_t)nb*968;
    for (int i = t; i < 968; i += 256){
      float4 u0 = ((const float4*)xg)[2*i];
      float4 u1 = ((const float4*)xg)[2*i+1];
      float e[8] = {u0.x,u0.y,u0.z,u0.w,u1.x,u1.y,u1.z,u1.w};
      int g = i*8;
      #pragma unroll
      for (int k = 0; k < 8; k++){
        int gg = g + k;
        int node = gg / 968, rem = gg - node*968;
        int ci = rem / 121, rem2 = rem - ci*121;
        int r = rem2 / 11, c = rem2 - r*11;
        xs[node*XND + ci*132 + r*12 + c] = f2bu(e[k]);
      }
    }
  }
  // bd cols 648..651 + zero cols 652..703
  for (int i = t; i < 8*56; i += 256){
    int node = i / 56, c = i - node*56;
    u16 v = 0;
    if (c < 4){
      float f = isbf ? bu2f(((const u16*)bdraw)[(size_t)(nb+node)*4 + c])
                     : ((const float*)bdraw)[(size_t)(nb+node)*4 + c];
      v = f2bu(fmaxf(f, 0.f));
    }
    h0[(size_t)(nb+node)*704 + 648 + c] = v;
  }
  __syncthreads();
  int q = t >> 6;               // wave-uniform quarter
  int node = (t >> 3) & 7, co = t & 7;
  const u16* xrow = xs + node*XND;
  float binit = bs[co];
  u16* outb = h0 + (size_t)(nb+node)*704 + co*81;
  if (q == 0){                  // out rows 0-2, in rows 0-4
    float acc[27];
    #pragma unroll
    for (int p = 0; p < 27; p++) acc[p] = binit;
    for (int ci = 0; ci < 8; ci++){
      float w[9];
      #pragma unroll
      for (int qq = 0; qq < 9; qq++) w[qq] = wsm[co*72 + ci*9 + qq];
      int xb = ci*132;
      float r0[11], r1[11], r2[11];
      CROW_LOAD(r0) CROW_LOAD(r1) CROW_LOAD(r2) CACC9(r0,r1,r2,0)
      CROW_LOAD(r0) CACC9(r1,r2,r0,1)
      CROW_LOAD(r1) CACC9(r2,r0,r1,2)
    }
    #pragma unroll
    for (int p = 0; p < 27; p++) outb[p] = f2bu(fmaxf(acc[p], 0.f));
  } else if (q == 1){           // out rows 3-4, in rows 3-6
    float acc[18];
    #pragma unroll
    for (int p = 0; p < 18; p++) acc[p] = binit;
    for (int ci = 0; ci < 8; ci++){
      float w[9];
      #pragma unroll
      for (int qq = 0; qq < 9; qq++) w[qq] = wsm[co*72 + ci*9 + qq];
      int xb = ci*132 + 36;
      float r0[11], r1[11], r2[11];
      CROW_LOAD(r0) CROW_LOAD(r1) CROW_LOAD(r2) CACC9(r0,r1,r2,0)
      CROW_LOAD(r0) CACC9(r1,r2,r0,1)
    }
    #pragma unroll
    for (int p = 0; p < 18; p++) outb[27+p] = f2bu(fmaxf(acc[p], 0.f));
  } else if (q == 2){           // out rows 5-6, in rows 5-8
    float acc[18];
    #pragma unroll
    for (int p = 0; p < 18; p++) acc[p] = binit;
    for (int ci = 0; ci < 8; ci++){
      float w[9];
      #pragma unroll
      for (int qq = 0; qq < 9; qq++) w[qq] = wsm[co*72 + ci*9 + qq];
      int xb = ci*132 + 60;
      float r0[11], r1[11], r2[11];
      CROW_LOAD(r0) CROW_LOAD(r1) CROW_LOAD(r2) CACC9(r0,r1,r2,0)
      CROW_LOAD(r0) CACC9(r1,r2,r0,1)
    }
    #pragma unroll
    for (int p = 0; p < 18; p++) outb[45+p] = f2bu(fmaxf(acc[p], 0.f));
  } else {                      // out rows 7-8, in rows 7-10
    float acc[18];
    #pragma unroll
    for (int p = 0; p < 18; p++) acc[p] = binit;
    for (int ci = 0; ci < 8; ci++){
      float w[9];
      #pragma unroll
      for (int qq = 0; qq < 9; qq++) w[qq] = wsm[co*72 + ci*9 + qq];
      int xb = ci*132 + 84;
      float r0[11], r1[11], r2[11];
      CROW_LOAD(r0) CROW_LOAD(r1) CROW_LOAD(r2) CACC9(r0,r1,r2,0)
      CROW_LOAD(r0) CACC9(r1,r2,r0,1)
    }
    #pragma unroll
    for (int p = 0; p < 18; p++) outb[63+p] = f2bu(fmaxf(acc[p], 0.f));
  }
}

// ---------- exclusive scan of degI -> rowptr + cursor + invd (single block) ----------
__global__ __launch_bounds__(1024) void scan_kernel(const int* __restrict__ degI,
                                                    int* __restrict__ rowptr,
                                                    int* __restrict__ cursor,
                                                    float* __restrict__ inv, int n){
  __shared__ int warp_sums[16];
  __shared__ int carry;
  int t = threadIdx.x;
  if (t == 0) carry = 0;
  __syncthreads();
  for (int base = 0; base < n; base += 8192){
    int i0 = base + t*8;
    int v[8]; int s = 0;
    #pragma unroll
    for (int q = 0; q < 8; q++){ int idx = i0+q; v[q] = (idx < n) ? degI[idx] : 0; s += v[q]; }
    int ts = s;
    #pragma unroll
    for (int off = 1; off < 64; off <<= 1){ int u = __shfl_up(ts, off); if ((t & 63) >= off) ts += u; }
    if ((t & 63) == 63) warp_sums[t >> 6] = ts;
    __syncthreads();
    if (t < 16){
      int wsv = warp_sums[t];
      #pragma unroll
      for (int off = 1; off < 16; off <<= 1){ int u = __shfl_up(wsv, off); if (t >= off) wsv += u; }
      warp_sums[t] = wsv;
    }
    __syncthreads();
    int blk = (t >= 64) ? warp_sums[(t >> 6) - 1] : 0;
    int excl = carry + blk + ts - s;
    #pragma unroll
    for (int q = 0; q < 8; q++){
      int idx = i0+q;
      if (idx < n){
        rowptr[idx] = excl; cursor[idx] = excl;
        inv[idx] = 1.0f / (float)(v[q] > 1 ? v[q] : 1);
      }
      excl += v[q];
    }
    int total = warp_sums[15];
    __syncthreads();
    if (t == 0) carry += total;
    __syncthreads();
  }
  if (t == 0) rowptr[n] = carry;
}

// ---------- bucket fill: ebuc[cursor[dst]++] = src ----------
__global__ void bucket_kernel(const int* __restrict__ esrc, const int* __restrict__ edst,
                              int* __restrict__ cursor, int* __restrict__ ebuc, int E){
  int e = blockIdx.x*256 + threadIdx.x;
  if (e < E){ int pos = atomicAdd(&cursor[edst[e]], 1); ebuc[pos] = esrc[e]; }
}

// ---------- gather-aggregate (bf16): out[n] = addbase[n] + scale[n]*sum src[nbr] ----------
#define GACC(U) { acc[0] += lo16f(U.x); acc[1] += hi16f(U.x); \
                  acc[2] += lo16f(U.y); acc[3] += hi16f(U.y); \
                  acc[4] += lo16f(U.z); acc[5] += hi16f(U.z); \
                  acc[6] += lo16f(U.w); acc[7] += hi16f(U.w); }
__global__ __launch_bounds__(256) void gather_agg_kernel(
    const u16* __restrict__ src_feat, int s_stride,
    const u16* __restrict__ addbase, int a_stride,
    const float* __restrict__ scale, u16* __restrict__ outp,
    const int* __restrict__ rowptr, const int* __restrict__ ebuc){
  int wid = threadIdx.x >> 6, lane = threadIdx.x & 63;
  int n = blockIdx.x*4 + wid;
  if (n >= NN) return;
  int half = lane >> 5;
  int sub  = lane & 31;
  int c0 = sub * 8;
  int beg = rowptr[n], end = rowptr[n+1];
  float acc[8] = {0.f,0.f,0.f,0.f,0.f,0.f,0.f,0.f};
  int j = beg + half;
  for (; j + 6 < end; j += 8){
    int s0 = ebuc[j], s1 = ebuc[j+2], s2 = ebuc[j+4], s3 = ebuc[j+6];
    uint4 u0 = *(const uint4*)(src_feat + (size_t)s0*s_stride + c0);
    uint4 u1 = *(const uint4*)(src_feat + (size_t)s1*s_stride + c0);
    uint4 u2 = *(const uint4*)(src_feat + (size_t)s2*s_stride + c0);
    uint4 u3 = *(const uint4*)(src_feat + (size_t)s3*s_stride + c0);
    GACC(u0) GACC(u1) GACC(u2) GACC(u3)
  }
  for (; j + 2 < end; j += 4){
    int s0 = ebuc[j], s1 = ebuc[j+2];
    uint4 u0 = *(const uint4*)(src_feat + (size_t)s0*s_stride + c0);
    uint4 u1 = *(const uint4*)(src_feat + (size_t)s1*s_stride + c0);
    GACC(u0) GACC(u1)
  }
  for (; j < end; j += 2){
    int s0 = ebuc[j];
    uint4 u0 = *(const uint4*)(src_feat + (size_t)s0*s_stride + c0);
    GACC(u0)
  }
  #pragma unroll
  for (int q = 0; q < 8; q++) acc[q] += __shfl_xor(acc[q], 32);
  if (half == 0){
    float sc = scale ? scale[n] : 1.f;
    #pragma unroll
    for (int q = 0; q < 8; q++) acc[q] *= sc;
    if (addbase){
      uint4 b = *(const uint4*)(addbase + (size_t)n*a_stride + c0);
      GACC(b)
    }
    uint4 o;
    o.x = (unsigned)f2bu(acc[0]) | ((unsigned)f2bu(acc[1]) << 16);
    o.y = (unsigned)f2bu(acc[2]) | ((unsigned)f2bu(acc[3]) << 16);
    o.z = (unsigned)f2bu(acc[4]) | ((unsigned)f2bu(acc[5]) << 16);
    o.w = (unsigned)f2bu(acc[6]) | ((unsigned)f2bu(acc[7]) << 16);
    *(uint4*)(outp + (size_t)n*256 + c0) = o;
  }
}

// ---------- MFMA bf16 GEMM: out = (A1 @ W1^T) + (A2 @ W2^T) + bias ----------
__global__ __launch_bounds__(256) void gemm_mfma_kernel(
    const u16* __restrict__ A1, int lda1, const u16* __restrict__ W1, int K1,
    const u16* __restrict__ A2, int lda2, const u16* __restrict__ W2, int K2,
    const float* __restrict__ bias, int ldc,
    u16* __restrict__ out_bf,
    void* __restrict__ out_emb,
    u16* __restrict__ out_relu_bf,
    const int* __restrict__ flags, int M){
  __shared__ u16 Asm[128][72];
  __shared__ u16 Wsm[128][72];
  int t = threadIdx.x;
  int wave = t >> 6, lane = t & 63;
  int wr = wave >> 1, wc = wave & 1;
  int m0 = blockIdx.x << 7;
  int o0 = blockIdx.y << 7;
  int lrow = t >> 1;
  int lk8  = (t & 1) << 3;
  int fr = lane & 15;
  int fkb = (lane >> 4) << 3;
  f32x4 acc[4][4] = {};

  for (int pass = 0; pass < 2; ++pass){
    const u16* A; const u16* W; int K, lda;
    if (pass == 0){ A = A1; W = W1; K = K1; lda = lda1; }
    else { if (!A2) break; A = A2; W = W2; K = K2; lda = lda2; }
    for (int k0 = 0; k0 < K; k0 += 64){
      int gm = m0 + lrow;
      int4 av0 = make_int4(0,0,0,0), av1 = av0, av2 = av0, av3 = av0;
      if (gm < M){
        const int4* ap = (const int4*)(A + (size_t)gm*lda + k0 + lk8);
        av0 = ap[0]; av1 = ap[2]; av2 = ap[4]; av3 = ap[6];
      }
      const int4* wp = (const int4*)(W + (size_t)(o0 + lrow)*K + k0 + lk8);
      int4 wv0 = wp[0], wv1 = wp[2], wv2 = wp[4], wv3 = wp[6];
      *(int4*)&Asm[lrow][lk8]      = av0;
      *(int4*)&Asm[lrow][lk8+16]   = av1;
      *(int4*)&Asm[lrow][lk8+32]   = av2;
      *(int4*)&Asm[lrow][lk8+48]   = av3;
      *(int4*)&Wsm[lrow][lk8]      = wv0;
      *(int4*)&Wsm[lrow][lk8+16]   = wv1;
      *(int4*)&Wsm[lrow][lk8+32]   = wv2;
      *(int4*)&Wsm[lrow][lk8+48]   = wv3;
      __syncthreads();
      #pragma unroll
      for (int kk = 0; kk < 2; kk++){
        int fk = kk*32 + fkb;
        bf16x8 af[4], wf[4];
        #pragma unroll
        for (int i = 0; i < 4; i++) af[i] = *(const bf16x8*)&Asm[wr*64 + i*16 + fr][fk];
        #pragma unroll
        for (int jj = 0; jj < 4; jj++) wf[jj] = *(const bf16x8*)&Wsm[wc*64 + jj*16 + fr][fk];
        #pragma unroll
        for (int i = 0; i < 4; i++)
          #pragma unroll
          for (int jj = 0; jj < 4; jj++)
            acc[i][jj] = __builtin_amdgcn_mfma_f32_16x16x32_bf16(af[i], wf[jj], acc[i][jj], 0, 0, 0);
      }
      __syncthreads();
    }
  }
  int isbf = flags[1];
  int fg = lane >> 4;
  #pragma unroll
  for (int i = 0; i < 4; i++){
    int rbase = m0 + wr*64 + i*16 + fg*4;
    #pragma unroll
    for (int jj = 0; jj < 4; jj++){
      int col = o0 + wc*64 + jj*16 + fr;
      float bv = bias[col];
      #pragma unroll
      for (int r = 0; r < 4; r++){
        int row = rbase + r;
        if (row < M){
          float v = acc[i][jj][r] + bv;
          size_t off = (size_t)row*ldc + col;
          if (out_bf)   out_bf[off] = f2bu(v);
          if (out_emb){
            if (isbf) ((u16*)out_emb)[off] = f2bu(v);
            else      ((float*)out_emb)[off] = v;
          }
          if (out_relu_bf) out_relu_bf[off] = f2bu(fmaxf(v, 0.f));
        }
      }
    }
  }
}

// ---------- relu + layernorm (bf16 in/out) ----------
__global__ __launch_bounds__(256) void relu_ln_kernel(
    const u16* __restrict__ inb, u16* __restrict__ outb,
    const float* __restrict__ g, const float* __restrict__ b){
  __shared__ float rs[4], rs2[4];
  int n = blockIdx.x, t = threadIdx.x;
  float v = fmaxf(bu2f(inb[(size_t)n*256 + t]), 0.f);
  float s = v, s2 = v*v;
  #pragma unroll
  for (int off = 1; off < 64; off <<= 1){ s += __shfl_xor(s, off); s2 += __shfl_xor(s2, off); }
  if ((t & 63) == 0){ rs[t>>6] = s; rs2[t>>6] = s2; }
  __syncthreads();
  float S  = rs[0]+rs[1]+rs[2]+rs[3];
  float S2 = rs2[0]+rs2[1]+rs2[2]+rs2[3];
  float mu  = S * (1.f/256.f);
  float var = S2 * (1.f/256.f) - mu*mu;
  float inv = rsqrtf(var + 1e-5f);
  outb[(size_t)n*256 + t] = f2bu((v - mu) * inv * g[t] + b[t]);
}

// ---------- head: z2 = z1 @ mp2^T + b2; log_softmax ----------
__global__ __launch_bounds__(256) void head_kernel(
    const u16* __restrict__ z1, const float* __restrict__ w2, const float* __restrict__ b2,
    void* __restrict__ outbase, size_t out_off, const int* __restrict__ flags, int M){
  __shared__ float wsm[1280];
  __shared__ float bs[5];
  int t = threadIdx.x;
  for (int i = t; i < 320; i += 256){
    float4 u = ((const float4*)w2)[i];
    wsm[4*i]=u.x; wsm[4*i+1]=u.y; wsm[4*i+2]=u.z; wsm[4*i+3]=u.w;
  }
  if (t < 5) bs[t] = b2[t];
  __syncthreads();
  int n = blockIdx.x*256 + t;
  if (n >= M) return;
  const u16* zp = z1 + (size_t)n*256;
  float acc[5];
  #pragma unroll
  for (int o = 0; o < 5; o++) acc[o] = bs[o];
  for (int k = 0; k < 256; k += 4){
    ushort4 zu = *(const ushort4*)(zp + k);
    float z0 = bu2f(zu.x), z1f = bu2f(zu.y), z2 = bu2f(zu.z), z3 = bu2f(zu.w);
    #pragma unroll
    for (int o = 0; o < 5; o++){
      const float* w = wsm + o*256 + k;
      acc[o] += z0*w[0] + z1f*w[1] + z2*w[2] + z3*w[3];
    }
  }
  float mx = acc[0];
  #pragma unroll
  for (int o = 1; o < 5; o++) mx = fmaxf(mx, acc[o]);
  float se = 0.f;
  #pragma unroll
  for (int o = 0; o < 5; o++) se += expf(acc[o] - mx);
  float lse = mx + logf(se);
  int isbf = flags[1];
  if (isbf){
    u16* op = (u16*)outbase + out_off + (size_t)n*5;
    #pragma unroll
    for (int o = 0; o < 5; o++) op[o] = f2bu(acc[o] - lse);
  } else {
    float* op = (float*)outbase + out_off + (size_t)n*5;
    #pragma unroll
    for (int o = 0; o < 5; o++) op[o] = acc[o] - lse;
  }
}

extern "C" void kernel_launch(void* const* d_in, const int* in_sizes, int n_in,
                              void* d_out, int out_size, void* d_ws, size_t ws_size,
                              hipStream_t stream){
  (void)in_sizes; (void)n_in; (void)out_size; (void)ws_size;
  const void* x    = d_in[0];
  const void* bd   = d_in[1];
  const void* eraw = d_in[2];

  char* ws = (char*)d_ws;
  const size_t OFF_H0 = 0;                                    // bf16 [NN][704]
  const size_t OFF_A  = OFF_H0 + (size_t)NN*704*2;            // bf16 [NN][256]
  const size_t OFF_B  = OFF_A  + (size_t)NN*256*2;            // bf16 [NN][256]  (bufAB low)
  const size_t OFF_C  = OFF_B  + (size_t)NN*256*2;            // bf16 [NN][256]  (bufAB high)
  const size_t OFF_DEG= OFF_C  + (size_t)NN*256*2;
  const size_t OFF_INV= OFF_DEG + (size_t)NN*4;
  const size_t OFF_EDG= OFF_INV + (size_t)NN*4;
  const size_t OFF_RP = OFF_EDG + (size_t)2*EE*4;
  const size_t OFF_CUR= OFF_RP  + (size_t)(NN+16)*4;
  const size_t OFF_EBU= OFF_CUR + (size_t)NN*4;
  const size_t OFF_FLG= OFF_EBU + (size_t)EE*4;
  const size_t OFF_PRM= OFF_FLG + 256;

  u16*   h0   = (u16*)(ws + OFF_H0);
  u16*   bufA = (u16*)(ws + OFF_A);
  u16*   bufB = (u16*)(ws + OFF_B);
  u16*   bufC = (u16*)(ws + OFF_C);
  u16*   bufAB= (u16*)(ws + OFF_B);   // [NN][512] aliases bufB+bufC
  int*   degI = (int*)(ws + OFF_DEG);
  float* invd = (float*)(ws + OFF_INV);
  int*   edg  = (int*)(ws + OFF_EDG);
  int*   rowp = (int*)(ws + OFF_RP);
  int*   curs = (int*)(ws + OFF_CUR);
  int*   ebuc = (int*)(ws + OFF_EBU);
  int*   flg  = (int*)(ws + OFF_FLG);
  char*  prm  = ws + OFF_PRM;
  const int* esrc = edg;
  const int* edst = edg + EE;

  static const int crows[15] = {1,1,256,1,256,1,1,1,1,1,1,1,1,1,1};
  static const int csk[15]   = {576,8,652,256,652,256,196608,768,196608,512,512,65536,256,1280,5};
  static const int cdk[15]   = {576,8,704,256,704,256,196608,768,196608,512,512,65536,256,1280,5};
  static const int ctobf[15] = {0,0,1,0,1,0,1,0,1,0,0,1,0,0,0};
  CanonTab tab;
  size_t po = 0;
  void* dsts[15];
  for (int i = 0; i < 15; i++){
    tab.src[i] = d_in[3+i];
    tab.rows[i] = crows[i]; tab.sk[i] = csk[i]; tab.dk[i] = cdk[i]; tab.tobf[i] = ctobf[i];
    dsts[i] = prm + po;
    tab.dst[i] = dsts[i];
    size_t bytes = (size_t)crows[i]*cdk[i] * (ctobf[i] ? 2 : 4);
    po += (bytes + 63) & ~(size_t)63;
  }
  // fused layer-0 W [512][704] bf16 + bias [512] f32 in fresh space
  u16*   c_l2w = (u16*)(prm + po);  po += (size_t)512*704*2;
  float* c_l2b = (float*)(prm + po); po += 512*4 + 64;
  tab.dst[4] = c_l2w;                    // lin_self_w -> rows 0..255
  tab.dst[2] = c_l2w + (size_t)256*704;  // lin_w      -> rows 256..511
  tab.dst[5] = c_l2b;                    // lin_self_b -> [0..255]
  tab.dst[3] = c_l2b + 256;              // lin_b      -> [256..511]

  const float* c_cw  = (const float*)dsts[0];
  const float* c_cb  = (const float*)dsts[1];
  const u16*   c_slw = (const u16*)dsts[6];
  const float* c_slb = (const float*)dsts[7];
  const u16*   c_srw = (const u16*)dsts[8];
  const float* c_lng = (const float*)dsts[9];
  const float* c_lnb = (const float*)dsts[10];
  const u16*   c_m1w = (const u16*)dsts[11];
  const float* c_m1b = (const float*)dsts[12];
  const float* c_m2w = (const float*)dsts[13];
  const float* c_m2b = (const float*)dsts[14];

  hipMemsetAsync(degI, 0, (size_t)NN*4, stream);
  sniff_kernel<<<1, 256, 0, stream>>>((const int*)eraw, (const u16*)x, flg);
  {
    dim3 cgrid(96, 15);
    canon_params_kernel<<<cgrid, 256, 0, stream>>>(tab, flg);
  }
  convert_edges_kernel<<<(2*EE + 255)/256, 256, 0, stream>>>(eraw, edg, degI, flg, 2*EE);
  conv_relu_kernel<<<NN/8, 256, 0, stream>>>(x, bd, c_cw, c_cb, flg, h0);
  scan_kernel<<<1, 1024, 0, stream>>>(degI, rowp, curs, invd, NN);
  bucket_kernel<<<(EE + 255)/256, 256, 0, stream>>>(esrc, edst, curs, ebuc, EE);

  dim3 ggrid((NN + 127)/128, 2);
  dim3 ggrid0((NN + 127)/128, 4);
  const int agrid = (NN + 3)/4;
  // layer 0 (fused): bufAB[:, 0:256] = self_x, bufAB[:, 256:512] = neigh
  gemm_mfma_kernel<<<ggrid0, 256, 0, stream>>>(h0, 704, c_l2w, 704,
      nullptr, 0, nullptr, 0, c_l2b, 512, bufAB, nullptr, nullptr, flg, NN);
  gather_agg_kernel<<<agrid, 256, 0, stream>>>(bufAB + 256, 512, bufAB, 512,
      nullptr, bufA, rowp, ebuc);

  for (int i = 0; i < 3; i++){
    gather_agg_kernel<<<agrid, 256, 0, stream>>>(bufA, 256, nullptr, 0,
        invd, bufC, rowp, ebuc);
    const u16*   L  = c_slw + (size_t)i*256*256;
    const float* Lb = c_slb + (size_t)i*256;
    const u16*   R  = c_srw + (size_t)i*256*256;
    if (i < 2){
      gemm_mfma_kernel<<<ggrid, 256, 0, stream>>>(bufC, 256, L, 256,
          bufA, 256, R, 256, Lb, 256, bufB, nullptr, nullptr, flg, NN);
      relu_ln_kernel<<<NN, 256, 0, stream>>>(bufB, bufA,
          c_lng + (size_t)i*256, c_lnb + (size_t)i*256);
    } else {
      gemm_mfma_kernel<<<ggrid, 256, 0, stream>>>(bufC, 256, L, 256,
          bufA, 256, R, 256, Lb, 256, nullptr, d_out, bufB, flg, NN);
    }
  }
  gemm_mfma_kernel<<<ggrid, 256, 0, stream>>>(bufB, 256, c_m1w, 256,
      nullptr, 0, nullptr, 0, c_m1b, 256, bufC, nullptr, nullptr, flg, NN);
  head_kernel<<<(NN + 255)/256, 256, 0, stream>>>(bufC, c_m2w, c_m2b,
      d_out, (size_t)NN*256, flg, NN);
}

// Round 12
// 830.427 us; speedup vs baseline: 1.1199x; 1.1199x over previous
//
#include <hip/hip_runtime.h>
#include <hip/hip_bf16.h>
#include <stdint.h>

#define NN 50000
#define EE 800000

typedef unsigned short u16;
typedef __attribute__((ext_vector_type(4))) float f32x4;
typedef __attribute__((ext_vector_type(8))) short bf16x8;

__device__ __forceinline__ float bu2f(u16 u){ return __uint_as_float(((unsigned)u)<<16); }
__device__ __forceinline__ u16 f2bu(float f){
  unsigned u = __float_as_uint(f);
  u += 0x7fffu + ((u>>16)&1u);      // round-to-nearest-even
  return (u16)(u>>16);
}
__device__ __forceinline__ float lo16f(unsigned u){ return __uint_as_float(u << 16); }
__device__ __forceinline__ float hi16f(unsigned u){ return __uint_as_float(u & 0xffff0000u); }

// ---------- sniff: flags[0] = edges are int64; flags[1] = float inputs are bf16 ----------
__global__ void sniff_kernel(const int* __restrict__ e, const u16* __restrict__ xu,
                             int* __restrict__ flags){
  __shared__ int nz, cnt;
  int t = threadIdx.x;
  if (t == 0){ nz = 0; cnt = 0; }
  __syncthreads();
  if (e[2*t + 1] != 0) atomicOr(&nz, 1);
  u16 u = xu[2*t];
  int ef = (u >> 7) & 0xFF;
  int ok = (u == 0) || (ef >= 118 && ef <= 132);
  atomicAdd(&cnt, ok);
  __syncthreads();
  if (t == 0){ flags[0] = (nz == 0) ? 1 : 0; flags[1] = (cnt >= 200) ? 1 : 0; }
}

// ---------- convert edges + degree (dst half) in one pass ----------
__global__ void convert_edges_kernel(const void* __restrict__ ep, int* __restrict__ outp,
                                     int* __restrict__ degI,
                                     const int* __restrict__ flags, int total){
  int i = blockIdx.x*256 + threadIdx.x;
  if (i >= total) return;
  int v;
  if (flags[0]) v = (int)((const long long*)ep)[i];
  else          v = ((const int*)ep)[i];
  outp[i] = v;
  if (i >= EE) atomicAdd(&degI[v], 1);   // dst entries
}

// ---------- canonicalize params: optional K-pad, to bf16 or fp32 ----------
struct CanonTab {
  const void* src[15];
  void*       dst[15];
  int rows[15];
  int sk[15];
  int dk[15];
  int tobf[15];
};

__global__ __launch_bounds__(256) void canon_params_kernel(CanonTab tab, const int* __restrict__ flags){
  int a = blockIdx.y;
  int isbf = flags[1];
  int rows = tab.rows[a], sk = tab.sk[a], dk = tab.dk[a], tobf = tab.tobf[a];
  int n = rows * dk;
  int base = (blockIdx.x*256 + threadIdx.x) * 8;
  if (base >= n) return;
  #pragma unroll
  for (int uu = 0; uu < 8; uu++){
    int i = base + uu;
    if (i >= n) break;
    int r = i / dk, c = i - r*dk;
    float v = 0.f;
    if (c < sk){
      size_t si = (size_t)r*sk + c;
      v = isbf ? bu2f(((const u16*)tab.src[a])[si]) : ((const float*)tab.src[a])[si];
    }
    if (tobf) ((u16*)tab.dst[a])[i] = f2bu(v);
    else      ((float*)tab.dst[a])[i] = v;
  }
}

// ---------- conv3x3 VALID + bias + concat(bd) + relu -> h0 bf16 [NN][704] ----------
// (round-7 version: empirically fastest, 168 us, VGPR 32, occupancy 82%)
__global__ __launch_bounds__(256) void conv_relu_kernel(
    const void* __restrict__ xraw, const void* __restrict__ bdraw,
    const float* __restrict__ cw, const float* __restrict__ cb,
    const int* __restrict__ flags, u16* __restrict__ h0){
  __shared__ float xs[968];    // 8*121
  __shared__ float wsm[576];   // 8*8*9
  __shared__ float bs[8];
  int n = blockIdx.x, t = threadIdx.x;
  int isbf = flags[1];
  if (isbf){
    const ushort4* xp = (const ushort4*)((const u16*)xraw + (size_t)n*968);
    if (t < 242){ ushort4 u = xp[t]; xs[4*t]=bu2f(u.x); xs[4*t+1]=bu2f(u.y); xs[4*t+2]=bu2f(u.z); xs[4*t+3]=bu2f(u.w); }
  } else {
    const float4* xp = (const float4*)((const float*)xraw + (size_t)n*968);
    if (t < 242){ float4 u = xp[t]; xs[4*t]=u.x; xs[4*t+1]=u.y; xs[4*t+2]=u.z; xs[4*t+3]=u.w; }
  }
  if (t < 144){ float4 u = ((const float4*)cw)[t]; wsm[4*t]=u.x; wsm[4*t+1]=u.y; wsm[4*t+2]=u.z; wsm[4*t+3]=u.w; }
  if (t < 8) bs[t] = cb[t];
  __syncthreads();
  u16* outr = h0 + (size_t)n*704;
  if (t < 216){
    int co = t & 7;
    int rowid = t >> 3;        // 0..26
    int oi = rowid / 3;        // 0..8
    int og = rowid - oi*3;     // 0..2
    float wreg[72];
    #pragma unroll
    for (int q = 0; q < 72; q++) wreg[q] = wsm[co*72 + q];
    float a0 = bs[co], a1 = a0, a2 = a0;
    #pragma unroll
    for (int ci = 0; ci < 8; ci++){
      #pragma unroll
      for (int ki = 0; ki < 3; ki++){
        const float* xb = xs + ci*121 + (oi+ki)*11 + og*3;
        float x0=xb[0], x1=xb[1], x2=xb[2], x3=xb[3], x4=xb[4];
        float w0=wreg[ci*9+ki*3+0], w1=wreg[ci*9+ki*3+1], w2=wreg[ci*9+ki*3+2];
        a0 += x0*w0 + x1*w1 + x2*w2;
        a1 += x1*w0 + x2*w1 + x3*w2;
        a2 += x2*w0 + x3*w1 + x4*w2;
      }
    }
    int colbase = co*81 + oi*9 + og*3;
    outr[colbase+0] = f2bu(fmaxf(a0, 0.f));
    outr[colbase+1] = f2bu(fmaxf(a1, 0.f));
    outr[colbase+2] = f2bu(fmaxf(a2, 0.f));
  } else if (t < 220){
    int jj = t - 216;
    float v = isbf ? bu2f(((const u16*)bdraw)[(size_t)n*4 + jj]) : ((const float*)bdraw)[(size_t)n*4 + jj];
    outr[648 + jj] = f2bu(fmaxf(v, 0.f));
  } else {
    for (int c = 652 + (t - 220); c < 704; c += 36) outr[c] = 0;
  }
}

// ---------- exclusive scan of degI -> rowptr + cursor + invd (single block) ----------
__global__ __launch_bounds__(1024) void scan_kernel(const int* __restrict__ degI,
                                                    int* __restrict__ rowptr,
                                                    int* __restrict__ cursor,
                                                    float* __restrict__ inv, int n){
  __shared__ int warp_sums[16];
  __shared__ int carry;
  int t = threadIdx.x;
  if (t == 0) carry = 0;
  __syncthreads();
  for (int base = 0; base < n; base += 8192){
    int i0 = base + t*8;
    int v[8]; int s = 0;
    #pragma unroll
    for (int q = 0; q < 8; q++){ int idx = i0+q; v[q] = (idx < n) ? degI[idx] : 0; s += v[q]; }
    int ts = s;
    #pragma unroll
    for (int off = 1; off < 64; off <<= 1){ int u = __shfl_up(ts, off); if ((t & 63) >= off) ts += u; }
    if ((t & 63) == 63) warp_sums[t >> 6] = ts;
    __syncthreads();
    if (t < 16){
      int wsv = warp_sums[t];
      #pragma unroll
      for (int off = 1; off < 16; off <<= 1){ int u = __shfl_up(wsv, off); if (t >= off) wsv += u; }
      warp_sums[t] = wsv;
    }
    __syncthreads();
    int blk = (t >= 64) ? warp_sums[(t >> 6) - 1] : 0;
    int excl = carry + blk + ts - s;
    #pragma unroll
    for (int q = 0; q < 8; q++){
      int idx = i0+q;
      if (idx < n){
        rowptr[idx] = excl; cursor[idx] = excl;
        inv[idx] = 1.0f / (float)(v[q] > 1 ? v[q] : 1);
      }
      excl += v[q];
    }
    int total = warp_sums[15];
    __syncthreads();
    if (t == 0) carry += total;
    __syncthreads();
  }
  if (t == 0) rowptr[n] = carry;
}

// ---------- bucket fill: ebuc[cursor[dst]++] = src ----------
__global__ void bucket_kernel(const int* __restrict__ esrc, const int* __restrict__ edst,
                              int* __restrict__ cursor, int* __restrict__ ebuc, int E){
  int e = blockIdx.x*256 + threadIdx.x;
  if (e < E){ int pos = atomicAdd(&cursor[edst[e]], 1); ebuc[pos] = esrc[e]; }
}

// ---------- gather + epilogue: val[n] = Z[n] + scale[n]*sum_nbr Y[nbr] ----------
// Y,Z are column halves of a [NN][512] buffer. mode 0: out=val; mode 1: out=LN(relu(val));
// mode 2: emb=val -> out_emb (dtype per flag), out=relu(val).
#define GACC(U) { acc[0] += lo16f(U.x); acc[1] += hi16f(U.x); \
                  acc[2] += lo16f(U.y); acc[3] += hi16f(U.y); \
                  acc[4] += lo16f(U.z); acc[5] += hi16f(U.z); \
                  acc[6] += lo16f(U.w); acc[7] += hi16f(U.w); }
__global__ __launch_bounds__(256) void gather_ln_kernel(
    const u16* __restrict__ Y, const u16* __restrict__ Z,
    const float* __restrict__ scale,
    const float* __restrict__ g, const float* __restrict__ b, int mode,
    u16* __restrict__ outA, void* __restrict__ out_emb,
    const int* __restrict__ flags,
    const int* __restrict__ rowptr, const int* __restrict__ ebuc){
  int wid = threadIdx.x >> 6, lane = threadIdx.x & 63;
  int n = blockIdx.x*4 + wid;
  if (n >= NN) return;
  int half = lane >> 5;
  int sub  = lane & 31;
  int c0 = sub * 8;
  int beg = rowptr[n], end = rowptr[n+1];
  float acc[8] = {0.f,0.f,0.f,0.f,0.f,0.f,0.f,0.f};
  int j = beg + half;
  for (; j + 6 < end; j += 8){
    int s0 = ebuc[j], s1 = ebuc[j+2], s2 = ebuc[j+4], s3 = ebuc[j+6];
    uint4 u0 = *(const uint4*)(Y + (size_t)s0*512 + c0);
    uint4 u1 = *(const uint4*)(Y + (size_t)s1*512 + c0);
    uint4 u2 = *(const uint4*)(Y + (size_t)s2*512 + c0);
    uint4 u3 = *(const uint4*)(Y + (size_t)s3*512 + c0);
    GACC(u0) GACC(u1) GACC(u2) GACC(u3)
  }
  for (; j + 2 < end; j += 4){
    int s0 = ebuc[j], s1 = ebuc[j+2];
    uint4 u0 = *(const uint4*)(Y + (size_t)s0*512 + c0);
    uint4 u1 = *(const uint4*)(Y + (size_t)s1*512 + c0);
    GACC(u0) GACC(u1)
  }
  for (; j < end; j += 2){
    int s0 = ebuc[j];
    uint4 u0 = *(const uint4*)(Y + (size_t)s0*512 + c0);
    GACC(u0)
  }
  #pragma unroll
  for (int q = 0; q < 8; q++) acc[q] += __shfl_xor(acc[q], 32);
  float sc = scale ? scale[n] : 1.f;
  float val[8];
  {
    uint4 zv = *(const uint4*)(Z + (size_t)n*512 + c0);
    val[0] = acc[0]*sc + lo16f(zv.x); val[1] = acc[1]*sc + hi16f(zv.x);
    val[2] = acc[2]*sc + lo16f(zv.y); val[3] = acc[3]*sc + hi16f(zv.y);
    val[4] = acc[4]*sc + lo16f(zv.z); val[5] = acc[5]*sc + hi16f(zv.z);
    val[6] = acc[6]*sc + lo16f(zv.w); val[7] = acc[7]*sc + hi16f(zv.w);
  }
  if (mode == 0){
    if (half == 0){
      uint4 o;
      o.x = (unsigned)f2bu(val[0]) | ((unsigned)f2bu(val[1]) << 16);
      o.y = (unsigned)f2bu(val[2]) | ((unsigned)f2bu(val[3]) << 16);
      o.z = (unsigned)f2bu(val[4]) | ((unsigned)f2bu(val[5]) << 16);
      o.w = (unsigned)f2bu(val[6]) | ((unsigned)f2bu(val[7]) << 16);
      *(uint4*)(outA + (size_t)n*256 + c0) = o;
    }
  } else if (mode == 1){
    float r[8]; float s = 0.f, s2 = 0.f;
    #pragma unroll
    for (int q = 0; q < 8; q++){ r[q] = fmaxf(val[q], 0.f); s += r[q]; s2 += r[q]*r[q]; }
    #pragma unroll
    for (int off = 1; off < 32; off <<= 1){ s += __shfl_xor(s, off); s2 += __shfl_xor(s2, off); }
    float mu  = s * (1.f/256.f);
    float var = s2 * (1.f/256.f) - mu*mu;
    float inv = rsqrtf(var + 1e-5f);
    if (half == 0){
      float4 g0 = *(const float4*)(g + c0), g1 = *(const float4*)(g + c0 + 4);
      float4 b0 = *(const float4*)(b + c0), b1 = *(const float4*)(b + c0 + 4);
      float gg[8] = {g0.x,g0.y,g0.z,g0.w,g1.x,g1.y,g1.z,g1.w};
      float bb[8] = {b0.x,b0.y,b0.z,b0.w,b1.x,b1.y,b1.z,b1.w};
      uint4 o; u16 e[8];
      #pragma unroll
      for (int q = 0; q < 8; q++) e[q] = f2bu((r[q]-mu)*inv*gg[q] + bb[q]);
      o.x = (unsigned)e[0] | ((unsigned)e[1] << 16);
      o.y = (unsigned)e[2] | ((unsigned)e[3] << 16);
      o.z = (unsigned)e[4] | ((unsigned)e[5] << 16);
      o.w = (unsigned)e[6] | ((unsigned)e[7] << 16);
      *(uint4*)(outA + (size_t)n*256 + c0) = o;
    }
  } else {
    if (half == 0){
      if (flags[1]){
        uint4 o;
        o.x = (unsigned)f2bu(val[0]) | ((unsigned)f2bu(val[1]) << 16);
        o.y = (unsigned)f2bu(val[2]) | ((unsigned)f2bu(val[3]) << 16);
        o.z = (unsigned)f2bu(val[4]) | ((unsigned)f2bu(val[5]) << 16);
        o.w = (unsigned)f2bu(val[6]) | ((unsigned)f2bu(val[7]) << 16);
        *(uint4*)((u16*)out_emb + (size_t)n*256 + c0) = o;
      } else {
        float* op = (float*)out_emb + (size_t)n*256 + c0;
        *(float4*)op     = make_float4(val[0], val[1], val[2], val[3]);
        *(float4*)(op+4) = make_float4(val[4], val[5], val[6], val[7]);
      }
      uint4 o;
      o.x = (unsigned)f2bu(fmaxf(val[0],0.f)) | ((unsigned)f2bu(fmaxf(val[1],0.f)) << 16);
      o.y = (unsigned)f2bu(fmaxf(val[2],0.f)) | ((unsigned)f2bu(fmaxf(val[3],0.f)) << 16);
      o.z = (unsigned)f2bu(fmaxf(val[4],0.f)) | ((unsigned)f2bu(fmaxf(val[5],0.f)) << 16);
      o.w = (unsigned)f2bu(fmaxf(val[6],0.f)) | ((unsigned)f2bu(fmaxf(val[7],0.f)) << 16);
      *(uint4*)(outA + (size_t)n*256 + c0) = o;
    }
  }
}

// ---------- MFMA bf16 GEMM: out[:, 0:256] = A@Wa^T + biasA; out[:, 256:512] = A@Wb^T + biasB ----
// A bf16 [M][lda]; Wa,Wb bf16 [256][K] row-major; K % 64 == 0. Tile 128x128, BK=64.
__global__ __launch_bounds__(256) void gemm_mfma_kernel(
    const u16* __restrict__ A, int lda,
    const u16* __restrict__ Wa, const u16* __restrict__ Wb,
    const float* __restrict__ biasA, const float* __restrict__ biasB,
    int K, int ldc,
    u16* __restrict__ out_bf, int M){
  __shared__ u16 Asm[128][72];
  __shared__ u16 Wsm[128][72];
  int t = threadIdx.x;
  int wave = t >> 6, lane = t & 63;
  int wr = wave >> 1, wc = wave & 1;
  int m0 = blockIdx.x << 7;
  int o0 = blockIdx.y << 7;
  const u16* W; const float* biasp;
  if (o0 < 256){ W = Wa + (size_t)o0*K; biasp = biasA + o0; }
  else         { W = Wb + (size_t)(o0-256)*K; biasp = biasB + (o0-256); }
  int lrow = t >> 1;
  int lk8  = (t & 1) << 3;
  int fr = lane & 15;
  int fkb = (lane >> 4) << 3;
  f32x4 acc[4][4] = {};

  for (int k0 = 0; k0 < K; k0 += 64){
    int gm = m0 + lrow;
    int4 av0 = make_int4(0,0,0,0), av1 = av0, av2 = av0, av3 = av0;
    if (gm < M){
      const int4* ap = (const int4*)(A + (size_t)gm*lda + k0 + lk8);
      av0 = ap[0]; av1 = ap[2]; av2 = ap[4]; av3 = ap[6];
    }
    const int4* wp = (const int4*)(W + (size_t)lrow*K + k0 + lk8);
    int4 wv0 = wp[0], wv1 = wp[2], wv2 = wp[4], wv3 = wp[6];
    *(int4*)&Asm[lrow][lk8]      = av0;
    *(int4*)&Asm[lrow][lk8+16]   = av1;
    *(int4*)&Asm[lrow][lk8+32]   = av2;
    *(int4*)&Asm[lrow][lk8+48]   = av3;
    *(int4*)&Wsm[lrow][lk8]      = wv0;
    *(int4*)&Wsm[lrow][lk8+16]   = wv1;
    *(int4*)&Wsm[lrow][lk8+32]   = wv2;
    *(int4*)&Wsm[lrow][lk8+48]   = wv3;
    __syncthreads();
    #pragma unroll
    for (int kk = 0; kk < 2; kk++){
      int fk = kk*32 + fkb;
      bf16x8 af[4], wf[4];
      #pragma unroll
      for (int i = 0; i < 4; i++) af[i] = *(const bf16x8*)&Asm[wr*64 + i*16 + fr][fk];
      #pragma unroll
      for (int jj = 0; jj < 4; jj++) wf[jj] = *(const bf16x8*)&Wsm[wc*64 + jj*16 + fr][fk];
      #pragma unroll
      for (int i = 0; i < 4; i++)
        #pragma unroll
        for (int jj = 0; jj < 4; jj++)
          acc[i][jj] = __builtin_amdgcn_mfma_f32_16x16x32_bf16(af[i], wf[jj], acc[i][jj], 0, 0, 0);
    }
    __syncthreads();
  }
  int fg = lane >> 4;
  #pragma unroll
  for (int i = 0; i < 4; i++){
    int rbase = m0 + wr*64 + i*16 + fg*4;
    #pragma unroll
    for (int jj = 0; jj < 4; jj++){
      int lcol = wc*64 + jj*16 + fr;
      float bv = biasp[lcol];
      int col = o0 + lcol;
      #pragma unroll
      for (int r = 0; r < 4; r++){
        int row = rbase + r;
        if (row < M)
          out_bf[(size_t)row*ldc + col] = f2bu(acc[i][jj][r] + bv);
      }
    }
  }
}

// ---------- head: z2 = z1 @ mp2^T + b2; log_softmax ----------
__global__ __launch_bounds__(256) void head_kernel(
    const u16* __restrict__ z1, const float* __restrict__ w2, const float* __restrict__ b2,
    void* __restrict__ outbase, size_t out_off, const int* __restrict__ flags, int M){
  __shared__ float wsm[1280];
  __shared__ float bs[5];
  int t = threadIdx.x;
  for (int i = t; i < 320; i += 256){
    float4 u = ((const float4*)w2)[i];
    wsm[4*i]=u.x; wsm[4*i+1]=u.y; wsm[4*i+2]=u.z; wsm[4*i+3]=u.w;
  }
  if (t < 5) bs[t] = b2[t];
  __syncthreads();
  int n = blockIdx.x*256 + t;
  if (n >= M) return;
  const u16* zp = z1 + (size_t)n*256;
  float acc[5];
  #pragma unroll
  for (int o = 0; o < 5; o++) acc[o] = bs[o];
  for (int k = 0; k < 256; k += 4){
    ushort4 zu = *(const ushort4*)(zp + k);
    float z0 = bu2f(zu.x), z1f = bu2f(zu.y), z2 = bu2f(zu.z), z3 = bu2f(zu.w);
    #pragma unroll
    for (int o = 0; o < 5; o++){
      const float* w = wsm + o*256 + k;
      acc[o] += z0*w[0] + z1f*w[1] + z2*w[2] + z3*w[3];
    }
  }
  float mx = acc[0];
  #pragma unroll
  for (int o = 1; o < 5; o++) mx = fmaxf(mx, acc[o]);
  float se = 0.f;
  #pragma unroll
  for (int o = 0; o < 5; o++) se += expf(acc[o] - mx);
  float lse = mx + logf(se);
  int isbf = flags[1];
  if (isbf){
    u16* op = (u16*)outbase + out_off + (size_t)n*5;
    #pragma unroll
    for (int o = 0; o < 5; o++) op[o] = f2bu(acc[o] - lse);
  } else {
    float* op = (float*)outbase + out_off + (size_t)n*5;
    #pragma unroll
    for (int o = 0; o < 5; o++) op[o] = acc[o] - lse;
  }
}

extern "C" void kernel_launch(void* const* d_in, const int* in_sizes, int n_in,
                              void* d_out, int out_size, void* d_ws, size_t ws_size,
                              hipStream_t stream){
  (void)in_sizes; (void)n_in; (void)out_size; (void)ws_size;
  const void* x    = d_in[0];
  const void* bd   = d_in[1];
  const void* eraw = d_in[2];

  char* ws = (char*)d_ws;
  const size_t OFF_H0 = 0;                                    // bf16 [NN][704]
  const size_t OFF_A  = OFF_H0 + (size_t)NN*704*2;            // bf16 [NN][256]
  const size_t OFF_YZ = OFF_A  + (size_t)NN*256*2;            // bf16 [NN][512]
  const size_t OFF_DEG= OFF_YZ + (size_t)NN*512*2;
  const size_t OFF_INV= OFF_DEG + (size_t)NN*4;
  const size_t OFF_EDG= OFF_INV + (size_t)NN*4;
  const size_t OFF_RP = OFF_EDG + (size_t)2*EE*4;
  const size_t OFF_CUR= OFF_RP  + (size_t)(NN+16)*4;
  const size_t OFF_EBU= OFF_CUR + (size_t)NN*4;
  const size_t OFF_FLG= OFF_EBU + (size_t)EE*4;
  const size_t OFF_PRM= OFF_FLG + 256;

  u16*   h0    = (u16*)(ws + OFF_H0);
  u16*   bufA  = (u16*)(ws + OFF_A);
  u16*   bufYZ = (u16*)(ws + OFF_YZ);           // [NN][512]
  u16*   bufC  = (u16*)(ws + OFF_YZ);           // [NN][256] reuse (YZ dead at mp1)
  int*   degI = (int*)(ws + OFF_DEG);
  float* invd = (float*)(ws + OFF_INV);
  int*   edg  = (int*)(ws + OFF_EDG);
  int*   rowp = (int*)(ws + OFF_RP);
  int*   curs = (int*)(ws + OFF_CUR);
  int*   ebuc = (int*)(ws + OFF_EBU);
  int*   flg  = (int*)(ws + OFF_FLG);
  char*  prm  = ws + OFF_PRM;
  const int* esrc = edg;
  const int* edst = edg + EE;

  static const int crows[15] = {1,1,256,1,256,1,1,1,1,1,1,1,1,1,1};
  static const int csk[15]   = {576,8,652,256,652,256,196608,768,196608,512,512,65536,256,1280,5};
  static const int cdk[15]   = {576,8,704,256,704,256,196608,768,196608,512,512,65536,256,1280,5};
  static const int ctobf[15] = {0,0,1,0,1,0,1,0,1,0,0,1,0,0,0};
  CanonTab tab;
  size_t po = 0;
  void* dsts[15];
  for (int i = 0; i < 15; i++){
    tab.src[i] = d_in[3+i];
    tab.rows[i] = crows[i]; tab.sk[i] = csk[i]; tab.dk[i] = cdk[i]; tab.tobf[i] = ctobf[i];
    dsts[i] = prm + po;
    tab.dst[i] = dsts[i];
    size_t bytes = (size_t)crows[i]*cdk[i] * (ctobf[i] ? 2 : 4);
    po += (bytes + 63) & ~(size_t)63;
  }
  float* c_zero = (float*)(prm + po); po += 1024 + 64;   // 256 zero floats

  const float* c_cw  = (const float*)dsts[0];
  const float* c_cb  = (const float*)dsts[1];
  const u16*   c_lw  = (const u16*)dsts[2];     // [256][704] (K-padded)
  const float* c_lb  = (const float*)dsts[3];
  const u16*   c_lsw = (const u16*)dsts[4];     // [256][704]
  const float* c_lsb = (const float*)dsts[5];
  const u16*   c_slw = (const u16*)dsts[6];     // [3*256][256]
  const float* c_slb = (const float*)dsts[7];
  const u16*   c_srw = (const u16*)dsts[8];
  const float* c_lng = (const float*)dsts[9];
  const float* c_lnb = (const float*)dsts[10];
  const u16*   c_m1w = (const u16*)dsts[11];
  const float* c_m1b = (const float*)dsts[12];
  const float* c_m2w = (const float*)dsts[13];
  const float* c_m2b = (const float*)dsts[14];

  hipMemsetAsync(degI, 0, (size_t)NN*4, stream);
  hipMemsetAsync(c_zero, 0, 1024, stream);
  sniff_kernel<<<1, 256, 0, stream>>>((const int*)eraw, (const u16*)x, flg);
  {
    dim3 cgrid(96, 15);
    canon_params_kernel<<<cgrid, 256, 0, stream>>>(tab, flg);
  }
  convert_edges_kernel<<<(2*EE + 255)/256, 256, 0, stream>>>(eraw, edg, degI, flg, 2*EE);
  conv_relu_kernel<<<NN, 256, 0, stream>>>(x, bd, c_cw, c_cb, flg, h0);
  scan_kernel<<<1, 1024, 0, stream>>>(degI, rowp, curs, invd, NN);
  bucket_kernel<<<(EE + 255)/256, 256, 0, stream>>>(esrc, edst, curs, ebuc, EE);

  dim3 g512((NN + 127)/128, 4);
  dim3 g256((NN + 127)/128, 2);
  const int agrid = (NN + 3)/4;

  // layer 0: YZ[:,0:256] = h0@lin_w^T + lb (gathered); YZ[:,256:512] = h0@lin_self_w^T + lsb
  gemm_mfma_kernel<<<g512, 256, 0, stream>>>(h0, 704, c_lw, c_lsw, c_lb, c_lsb,
      704, 512, bufYZ, NN);
  gather_ln_kernel<<<agrid, 256, 0, stream>>>(bufYZ, bufYZ + 256, nullptr,
      nullptr, nullptr, 0, bufA, nullptr, flg, rowp, ebuc);

  // SAGE layers: YZ[:,0:256] = h@L^T (gathered, scaled by invd); YZ[:,256:512] = h@R^T + Lb
  for (int i = 0; i < 3; i++){
    const u16*   L  = c_slw + (size_t)i*256*256;
    const u16*   R  = c_srw + (size_t)i*256*256;
    const float* Lb = c_slb + (size_t)i*256;
    gemm_mfma_kernel<<<g512, 256, 0, stream>>>(bufA, 256, L, R, c_zero, Lb,
        256, 512, bufYZ, NN);
    if (i < 2){
      gather_ln_kernel<<<agrid, 256, 0, stream>>>(bufYZ, bufYZ + 256, invd,
          c_lng + (size_t)i*256, c_lnb + (size_t)i*256, 1, bufA, nullptr, flg, rowp, ebuc);
    } else {
      gather_ln_kernel<<<agrid, 256, 0, stream>>>(bufYZ, bufYZ + 256, invd,
          nullptr, nullptr, 2, bufA, d_out, flg, rowp, ebuc);
    }
  }
  // mp1: bufC = relu_h @ m1w^T + m1b  (bufYZ dead -> reuse as bufC)
  gemm_mfma_kernel<<<g256, 256, 0, stream>>>(bufA, 256, c_m1w, nullptr, c_m1b, nullptr,
      256, 256, bufC, NN);
  head_kernel<<<(NN + 255)/256, 256, 0, stream>>>(bufC, c_m2w, c_m2b,
      d_out, (size_t)NN*256, flg, NN);
}